// Round 1
// 194.283 us; speedup vs baseline: 1.0073x; 1.0073x over previous
//
#include <hip/hip_runtime.h>
#include <math.h>

// Problem constants
#define BB   512   // batch
#define TT   256   // timesteps
#define CNNC 512   // channels
#define VV   37    // vocab
#define HH   8     // hidden
#define G4   32    // 4*H
#define CH   32    // scan chunk length (timesteps)
#define CW   (CH * 128)   // chunk words per k_lstm block: 32t x 32g x 4seq (16 KB)

#define L2E 1.4426950408889634f

// native 4-float vector for nontemporal builtins (HIP float4 is a class type)
typedef float f4_t __attribute__((ext_vector_type(4)));

// Async global->LDS copy, 16 B per lane. LDS dest = wave-uniform base + lane*16.
__device__ __forceinline__ void async_copy16(const float* g, float* l) {
    __builtin_amdgcn_global_load_lds(
        (__attribute__((address_space(1))) void*)g,
        (__attribute__((address_space(3))) void*)l, 16, 0, 0);
}

// DPP cross-lane mov: pure VALU latency. quad_perm 0xB1=xor1, 0x4E=xor2,
// 0x1B=xor3; 0x141=row_half_mirror (xor7); 0x140=row_mirror (xor15).
template <int CTRL>
__device__ __forceinline__ float dpp_f(float x) {
    int r = __builtin_amdgcn_update_dpp(0, __float_as_int(x), CTRL, 0xF, 0xF, true);
    return __int_as_float(r);
}

__device__ __forceinline__ float rcp_f(float x) { return __builtin_amdgcn_rcpf(x); }
__device__ __forceinline__ float exp2_f(float x) { return __builtin_amdgcn_exp2f(x); }

// ---------------------------------------------------------------------------
// Kernel 1: avg-pool(features) @ W_in.T partial -> featp[quarter][B][V]
// (unchanged: BW-bound on the 51 MB feature read, at roofline)
// ---------------------------------------------------------------------------
__global__ __launch_bounds__(256) void k_feat(const float* __restrict__ features,
                                              const float* __restrict__ W_in,
                                              const float* __restrict__ b_in,
                                              float* __restrict__ featp) {
    __shared__ __align__(16) float raw[128 * 49];    // 25088 B
    __shared__ float pooled[128];
    const int b = blockIdx.x, qt = blockIdx.y, tid = threadIdx.x;
    const f4_t* src =
        (const f4_t*)(features + (size_t)b * CNNC * 49 + qt * (128 * 49));
    f4_t* dst = (f4_t*)raw;
    for (int i = tid; i < 128 * 49 / 4; i += 256)
        dst[i] = __builtin_nontemporal_load(&src[i]);
    __syncthreads();
    if (tid < 128) {
        const float* p = raw + tid * 49;
        float s = 0.f;
        #pragma unroll
        for (int i = 0; i < 49; ++i) s += p[i];
        pooled[tid] = s;
    }
    __syncthreads();
    const int v = tid >> 2, pp = tid & 3;
    if (v < VV) {
        const float* w = W_in + v * CNNC + qt * 128 + pp * 32;
        const float* q = pooled + pp * 32;
        float s = 0.f;
        #pragma unroll
        for (int i = 0; i < 32; ++i) s += q[i] * w[i];
        s += __shfl_xor(s, 1);
        s += __shfl_xor(s, 2);
        if (pp == 0)
            featp[(qt * BB + b) * VV + v] =
                s * (1.f / 49.f) + (qt == 0 ? b_in[v] : 0.f);
    }
}

// ---------------------------------------------------------------------------
// Kernel 2: xproj[bg128][t][g][s4] = -(x_t @ W_ih.T + b_ih + b_hh) * scale_g
// (unchanged: BW-bound on captions read + xproj write, at roofline)
// ---------------------------------------------------------------------------
#define CAPS 1188   // per-seq caption stage stride (1184+4)
#define SOS  132    // out-stage stride per t (128+4)
__global__ __launch_bounds__(256) void k_xproj(const float* __restrict__ captions,
                                               const float* __restrict__ W_ih,
                                               const float* __restrict__ b_ih,
                                               const float* __restrict__ b_hh,
                                               const float* __restrict__ featp,
                                               float* __restrict__ xproj) {
    __shared__ float W[G4 * VV];                     // 4736 B
    __shared__ float bias[G4];
    __shared__ float cap[4 * CAPS];                  // 19008 B
    __shared__ __align__(16) float so[32 * SOS];     // 16896 B
    const int bg = blockIdx.x, tile = blockIdx.y;
    const int tid = threadIdx.x;
    for (int i = tid; i < G4 * VV; i += 256) W[i] = W_ih[i];
    if (tid < G4) bias[tid] = b_ih[tid] + b_hh[tid];

    // stage caption rows [start, start+32) for the block's 4 sequences
    const int t0 = tile * 32;
    const int start = (tile == 0) ? 0 : t0 - 1;
    for (int i = tid; i < 4 * 1184; i += 256) {
        const int s2 = i / 1184;                      // const-div -> mul/shift
        const int off = i - s2 * 1184;
        cap[s2 * CAPS + off] = __builtin_nontemporal_load(
            &captions[((size_t)(bg * 4 + s2) * TT + start) * VV + off]);
    }
    __syncthreads();

    const int tl = tid >> 3;             // 0..31 local t
    const int s  = (tid >> 1) & 3;       // seq within block
    const int r  = tid & 1;              // gate half (0: rows 0-15, 1: 16-31)
    const int t  = t0 + tl;
    const int b  = bg * 4 + s;

    float xr[VV];
    if (tile == 0 && tl == 0) {
        #pragma unroll
        for (int v = 0; v < VV; ++v)
            xr[v] = featp[b * VV + v] + featp[(BB + b) * VV + v] +
                    featp[(2 * BB + b) * VV + v] + featp[(3 * BB + b) * VV + v];
    } else {
        const int lr = (tile == 0) ? tl - 1 : tl;
        const float* x = &cap[s * CAPS + lr * VV];
        #pragma unroll
        for (int v = 0; v < VV; ++v) xr[v] = x[v];
    }

    const int g0 = r * 16;
    float acc[16];
    #pragma unroll
    for (int g = 0; g < 16; ++g) acc[g] = bias[g0 + g];
    #pragma unroll
    for (int v = 0; v < VV; ++v) {
        const float xv = xr[v];
        #pragma unroll
        for (int g = 0; g < 16; ++g) acc[g] += xv * W[(g0 + g) * VV + v];
    }
    #pragma unroll
    for (int g = 0; g < 16; ++g) {
        const int gg = g0 + g;
        const float sc = (gg >= 16 && gg < 24) ? (-2.f * L2E) : (-L2E);
        so[tl * SOS + gg * 4 + s] = acc[g] * sc;
    }
    __syncthreads();

    // write the 16 KB chunk [t][g][s4] contiguously
    float* chunk = xproj + ((size_t)bg * TT + t0) * 128;
    for (int i = tid; i < 1024; i += 256) {
        const int t2 = i >> 5, rest = i & 31;
        f4_t val = *(const f4_t*)&so[t2 * SOS + rest * 4];
        *(f4_t*)&chunk[t2 * 128 + rest * 4] = val;
    }
}

// ---------------------------------------------------------------------------
// Kernel 3 (FUSED): sequential scan + output softmax.
//   wave 0  (tid 0-63):   16 lanes/sequence scan, identical structure to the
//                         previous k_lstm, but h goes to a double-buffered LDS
//                         chunk buffer instead of global hbuf. c is tracked
//                         pre-scaled by -2*L2E (one fewer op on the serial
//                         critical path).
//   waves 1-2 (tid 64-191): one chunk behind, each lane owns one (seq,t) row:
//                         37-logit dot (ds_read_b128 of W_out, 74 reads/row),
//                         softmax, direct store to out. Runs entirely inside
//                         wave 0's latency-bound chunk (~2950 cyc vs ~1500).
// Sync: raw s_barrier + lgkmcnt(0) only -- NO vmcnt drain, so the triple-
// buffered global_load_lds prefetch pipeline (vmcnt 16/48/32) is preserved.
// LDS: 49280 (buf) + 8192 (hst) + 1184 (Wo) + 148 (bo) = 58.8 KB.
// ---------------------------------------------------------------------------
__global__ __launch_bounds__(192) void k_lstm(const float* __restrict__ W_hh,
                                              const float* __restrict__ xproj,
                                              const float* __restrict__ W_out,
                                              const float* __restrict__ b_out,
                                              float* __restrict__ out) {
    __shared__ __align__(16) float buf[3 * CW + 128];   // 3 x 16 KB + pad
    __shared__ __align__(16) float hst[2 * 4 * CH * HH]; // h double buffer, 8 KB
    __shared__ __align__(16) float Wo[VV * HH];
    __shared__ float bo[VV];

    const int tid  = threadIdx.x;
    const int wv   = tid >> 6;        // 0: scan; 1,2: output
    const int lane = tid & 63;
    const int bg   = blockIdx.x;      // 0..127
    const float* xp = xproj + (size_t)bg * (TT * 128);

    if (wv == 0) {
        // prefetch chunks 0 and 1 immediately
        #pragma unroll
        for (int it = 0; it < 16; ++it)
            async_copy16(xp + (it * 64 + lane) * 4, &buf[it * 256]);
        #pragma unroll
        for (int it = 0; it < 16; ++it)
            async_copy16(xp + CW + (it * 64 + lane) * 4, &buf[CW + it * 256]);
    } else {
        // output waves stage W_out / b_out meanwhile
        const int l2 = tid - 64;          // 0..127
        for (int i = l2; i < VV * HH; i += 128) Wo[i] = W_out[i];
        if (l2 < VV) bo[l2] = b_out[l2];
    }

    // ---- wave-0 persistent scan state ----
    const int s4 = lane >> 4;
    const int q  = lane & 15;
    const int j  = q >> 1;
    const int r  = q & 1;
    float wA[HH], wB[HH];
    int roff = 0;
    if (wv == 0) {
        const int rowA = r * 8 + j;          // i or f
        const int rowB = 16 + r * 8 + j;     // g or o
        const float scA = -L2E;
        const float scB = r ? -L2E : (-2.f * L2E);
        #pragma unroll
        for (int m = 0; m < HH; ++m) {
            wA[m] = scA * W_hh[rowA * HH + (j ^ m)];
            wB[m] = scB * W_hh[rowB * HH + (j ^ m)];
        }
        roff = rowA * 4 + s4;
    }
    float h = 0.f, c = 0.f;                  // c holds cs = -2*L2E * c_true

    // ---- output-wave constants ----
    const int orow = (wv - 1) * 64 + lane;   // 0..127 (wv=1,2)
    const int os   = orow >> 5;              // seq in block
    const int otl  = orow & 31;              // local t

    for (int it = 0; it < 9; ++it) {
        if (wv == 0) {
            if (it < 8) {
                if (it == 0)      asm volatile("s_waitcnt vmcnt(16)" ::: "memory");
                else if (it == 7) asm volatile("s_waitcnt vmcnt(32)" ::: "memory");
                else              asm volatile("s_waitcnt vmcnt(48)" ::: "memory");

                const float* base = &buf[(it % 3) * CW] + roff;
                float* hsl = &hst[((it & 1) * 4 + s4) * (CH * HH) + j];
                float pA = base[0], pB = base[64];
                #pragma unroll
                for (int tl = 0; tl < CH; ++tl) {
                    const float nA = base[(tl + 1) * 128];
                    const float nB = base[(tl + 1) * 128 + 64];

                    const float ha0 = h;
                    const float ha1 = dpp_f<0x4E>(h);             // j^1
                    const float ha3 = dpp_f<0x141>(h);            // j^3
                    const float ha2 = dpp_f<0x4E>(ha3);           // j^2
                    const float ha7 = dpp_f<0x140>(h);            // j^7
                    const float ha4 = dpp_f<0x141>(ha7);          // j^4
                    const float ha5 = dpp_f<0x4E>(ha4);           // j^5
                    const float ha6 = dpp_f<0x1B>(ha7);           // j^6

                    float a0 = fmaf(wA[0], ha0, pA);
                    a0 = fmaf(wA[1], ha1, a0);
                    a0 = fmaf(wA[2], ha2, a0);
                    a0 = fmaf(wA[3], ha3, a0);
                    float a1 = wA[4] * ha4;
                    a1 = fmaf(wA[5], ha5, a1);
                    a1 = fmaf(wA[6], ha6, a1);
                    a1 = fmaf(wA[7], ha7, a1);
                    const float npA = a0 + a1;
                    float b0 = fmaf(wB[0], ha0, pB);
                    b0 = fmaf(wB[1], ha1, b0);
                    b0 = fmaf(wB[2], ha2, b0);
                    b0 = fmaf(wB[3], ha3, b0);
                    float b1 = wB[4] * ha4;
                    b1 = fmaf(wB[5], ha5, b1);
                    b1 = fmaf(wB[6], ha6, b1);
                    b1 = fmaf(wB[7], ha7, b1);
                    const float npB = b0 + b1;

                    const float eA = rcp_f(1.f + exp2_f(npA));    // r=0: i ; r=1: f
                    const float uB = rcp_f(1.f + exp2_f(npB));    // r=0: raw g ; r=1: o
                    // gg' = -2*L2E * tanh-from-sigmoid = -4*L2E*uB + 2*L2E
                    const float gg = fmaf(-4.f * L2E, uB, 2.f * L2E);

                    const float myU = r ? eA : eA * gg;           // r=0: -2L2E*i*g ; r=1: f
                    const float otU = dpp_f<0xB1>(myU);
                    const float fg  = r ? myU : otU;
                    const float igg = r ? otU : myU;
                    const float ogx = dpp_f<0xB1>(uB);
                    const float og  = r ? uB : ogx;

                    c = fmaf(fg, c, igg);                         // cs update
                    const float th = fmaf(2.f, rcp_f(1.f + exp2_f(c)), -1.f);
                    h = og * th;
                    if (r == 0) hsl[tl * HH] = h;                 // off critical path
                    pA = nA; pB = nB;
                }
                if (it + 2 < TT / CH) {
                    const float* src = xp + (size_t)(it + 2) * CW;
                    float* db = &buf[((it + 2) % 3) * CW];
                    #pragma unroll
                    for (int k = 0; k < 16; ++k)
                        async_copy16(src + (k * 64 + lane) * 4, &db[k * 256]);
                }
            }
        } else if (it >= 1) {
            const int pk = it - 1;                                 // chunk to emit
            const f4_t* hp =
                (const f4_t*)&hst[(((pk & 1) * 4 + os) * CH + otl) * HH];
            const f4_t h0 = hp[0], h1 = hp[1];
            const f4_t* W4 = (const f4_t*)Wo;
            float z[VV];
            float m = -1e30f;
            #pragma unroll
            for (int v = 0; v < VV; ++v) {
                const f4_t w0 = W4[v * 2], w1 = W4[v * 2 + 1];
                float sv = bo[v];
                sv = fmaf(h0.x, w0.x, sv); sv = fmaf(h0.y, w0.y, sv);
                sv = fmaf(h0.z, w0.z, sv); sv = fmaf(h0.w, w0.w, sv);
                sv = fmaf(h1.x, w1.x, sv); sv = fmaf(h1.y, w1.y, sv);
                sv = fmaf(h1.z, w1.z, sv); sv = fmaf(h1.w, w1.w, sv);
                z[v] = sv;
                m = fmaxf(m, sv);
            }
            float sum = 0.f;
            #pragma unroll
            for (int v = 0; v < VV; ++v) {
                z[v] = exp2_f((z[v] - m) * L2E);
                sum += z[v];
            }
            const float rs = rcp_f(sum);
            const int b = bg * 4 + os;
            const int t = pk * CH + otl;
            float* op = out + ((size_t)b * TT + t) * VV;
            #pragma unroll
            for (int v = 0; v < VV; ++v) op[v] = z[v] * rs;
        }
        // LDS-visibility barrier WITHOUT vmcnt drain (preserve prefetch queue)
        asm volatile("s_waitcnt lgkmcnt(0)" ::: "memory");
        __builtin_amdgcn_s_barrier();
        __builtin_amdgcn_sched_barrier(0);
    }
}

// ---------------------------------------------------------------------------
// Workspace (floats): featp@0 (4*512*37=75,776) | xproj@81920 (4,194,304)
// hbuf eliminated (h stays in LDS inside the fused kernel).
// ---------------------------------------------------------------------------
extern "C" void kernel_launch(void* const* d_in, const int* in_sizes, int n_in,
                              void* d_out, int out_size, void* d_ws, size_t ws_size,
                              hipStream_t stream) {
    const float* features = (const float*)d_in[0];
    const float* captions = (const float*)d_in[1];
    const float* W_in     = (const float*)d_in[2];
    const float* b_in     = (const float*)d_in[3];
    const float* W_ih     = (const float*)d_in[4];
    const float* W_hh     = (const float*)d_in[5];
    const float* b_ih     = (const float*)d_in[6];
    const float* b_hh     = (const float*)d_in[7];
    const float* W_out    = (const float*)d_in[8];
    const float* b_out    = (const float*)d_in[9];
    float* out = (float*)d_out;

    float* ws    = (float*)d_ws;
    float* featp = ws;
    float* xproj = ws + 81920;

    k_feat <<<dim3(BB, 4),  256, 0, stream>>>(features, W_in, b_in, featp);
    k_xproj<<<dim3(128, 8), 256, 0, stream>>>(captions, W_ih, b_ih, b_hh, featp, xproj);
    k_lstm <<<128,          192, 0, stream>>>(W_hh, xproj, W_out, b_out, out);
}

// Round 2
// 192.243 us; speedup vs baseline: 1.0180x; 1.0106x over previous
//
#include <hip/hip_runtime.h>
#include <math.h>

// Problem constants
#define BB   512   // batch
#define TT   256   // timesteps
#define CNNC 512   // channels
#define VV   37    // vocab
#define HH   8     // hidden
#define G4   32    // 4*H
#define CH   16    // scan chunk length (timesteps)
#define NCH  (TT / CH)      // 16 chunks
#define CHW  (CH * 128)     // words per chunk of one 4-seq group (8 KB)

#define L2E 1.4426950408889634f

// native vector types for vector loads/stores (HIP float4 is a class type)
typedef float f4_t __attribute__((ext_vector_type(4)));
typedef float f2_t __attribute__((ext_vector_type(2)));

// DPP cross-lane mov: pure VALU latency. quad_perm 0xB1=xor1, 0x4E=xor2,
// 0x1B=xor3; 0x141=row_half_mirror (xor7); 0x140=row_mirror (xor15).
template <int CTRL>
__device__ __forceinline__ float dpp_f(float x) {
    int r = __builtin_amdgcn_update_dpp(0, __float_as_int(x), CTRL, 0xF, 0xF, true);
    return __int_as_float(r);
}

__device__ __forceinline__ float rcp_f(float x) { return __builtin_amdgcn_rcpf(x); }
__device__ __forceinline__ float exp2_f(float x) { return __builtin_amdgcn_exp2f(x); }

// ---------------------------------------------------------------------------
// Kernel 1: avg-pool(features) @ W_in.T partial -> featp[quarter][B][V]
// (unchanged: BW-bound on the 51 MB feature read, at roofline)
// ---------------------------------------------------------------------------
__global__ __launch_bounds__(256) void k_feat(const float* __restrict__ features,
                                              const float* __restrict__ W_in,
                                              const float* __restrict__ b_in,
                                              float* __restrict__ featp) {
    __shared__ __align__(16) float raw[128 * 49];    // 25088 B
    __shared__ float pooled[128];
    const int b = blockIdx.x, qt = blockIdx.y, tid = threadIdx.x;
    const f4_t* src =
        (const f4_t*)(features + (size_t)b * CNNC * 49 + qt * (128 * 49));
    f4_t* dst = (f4_t*)raw;
    for (int i = tid; i < 128 * 49 / 4; i += 256)
        dst[i] = __builtin_nontemporal_load(&src[i]);
    __syncthreads();
    if (tid < 128) {
        const float* p = raw + tid * 49;
        float s = 0.f;
        #pragma unroll
        for (int i = 0; i < 49; ++i) s += p[i];
        pooled[tid] = s;
    }
    __syncthreads();
    const int v = tid >> 2, pp = tid & 3;
    if (v < VV) {
        const float* w = W_in + v * CNNC + qt * 128 + pp * 32;
        const float* q = pooled + pp * 32;
        float s = 0.f;
        #pragma unroll
        for (int i = 0; i < 32; ++i) s += q[i] * w[i];
        s += __shfl_xor(s, 1);
        s += __shfl_xor(s, 2);
        if (pp == 0)
            featp[(qt * BB + b) * VV + v] =
                s * (1.f / 49.f) + (qt == 0 ? b_in[v] : 0.f);
    }
}

// ---------------------------------------------------------------------------
// Kernel 2: xproj = -(x_t @ W_ih.T + b_ih + b_hh) * scale_g, pre-permuted.
// NEW word layout per t (128 words): word = ((gg&15)*4 + s4)*2 + (gg>>4)
// so that a scan lane's (A-row, B-row) pre-activations are ADJACENT ->
// one coalesced global_load_dwordx2 per lane per timestep in k_lstm.
// ---------------------------------------------------------------------------
#define CAPS 1188   // per-seq caption stage stride (1184+4)
#define SOS  132    // out-stage stride per t (128+4)
__global__ __launch_bounds__(256) void k_xproj(const float* __restrict__ captions,
                                               const float* __restrict__ W_ih,
                                               const float* __restrict__ b_ih,
                                               const float* __restrict__ b_hh,
                                               const float* __restrict__ featp,
                                               float* __restrict__ xproj) {
    __shared__ float W[G4 * VV];                     // 4736 B
    __shared__ float bias[G4];
    __shared__ float cap[4 * CAPS];                  // 19008 B
    __shared__ __align__(16) float so[32 * SOS];     // 16896 B
    const int bg = blockIdx.x, tile = blockIdx.y;
    const int tid = threadIdx.x;
    for (int i = tid; i < G4 * VV; i += 256) W[i] = W_ih[i];
    if (tid < G4) bias[tid] = b_ih[tid] + b_hh[tid];

    // stage caption rows [start, start+32) for the block's 4 sequences
    const int t0 = tile * 32;
    const int start = (tile == 0) ? 0 : t0 - 1;
    for (int i = tid; i < 4 * 1184; i += 256) {
        const int s2 = i / 1184;                      // const-div -> mul/shift
        const int off = i - s2 * 1184;
        cap[s2 * CAPS + off] = __builtin_nontemporal_load(
            &captions[((size_t)(bg * 4 + s2) * TT + start) * VV + off]);
    }
    __syncthreads();

    const int tl = tid >> 3;             // 0..31 local t
    const int s  = (tid >> 1) & 3;       // seq within block
    const int r  = tid & 1;              // gate half (0: rows 0-15, 1: 16-31)
    const int b  = bg * 4 + s;

    float xr[VV];
    if (tile == 0 && tl == 0) {
        #pragma unroll
        for (int v = 0; v < VV; ++v)
            xr[v] = featp[b * VV + v] + featp[(BB + b) * VV + v] +
                    featp[(2 * BB + b) * VV + v] + featp[(3 * BB + b) * VV + v];
    } else {
        const int lr = (tile == 0) ? tl - 1 : tl;
        const float* x = &cap[s * CAPS + lr * VV];
        #pragma unroll
        for (int v = 0; v < VV; ++v) xr[v] = x[v];
    }

    const int g0 = r * 16;
    float acc[16];
    #pragma unroll
    for (int g = 0; g < 16; ++g) acc[g] = bias[g0 + g];
    #pragma unroll
    for (int v = 0; v < VV; ++v) {
        const float xv = xr[v];
        #pragma unroll
        for (int g = 0; g < 16; ++g) acc[g] += xv * W[(g0 + g) * VV + v];
    }
    #pragma unroll
    for (int g = 0; g < 16; ++g) {
        const int gg = g0 + g;
        const float sc = (gg >= 16 && gg < 24) ? (-2.f * L2E) : (-L2E);
        const int word = ((gg & 15) * 4 + s) * 2 + (gg >> 4);  // pair layout
        so[tl * SOS + word] = acc[g] * sc;
    }
    __syncthreads();

    // write the 16 KB tile [t][word] contiguously
    float* chunk = xproj + ((size_t)bg * TT + t0) * 128;
    for (int i = tid; i < 1024; i += 256) {
        const int t2 = i >> 5, rest = i & 31;
        f4_t val = *(const f4_t*)&so[t2 * SOS + rest * 4];
        *(f4_t*)&chunk[t2 * 128 + rest * 4] = val;
    }
}

// ---------------------------------------------------------------------------
// Kernel 3 (FUSED): sequential scan + output softmax.
//   wave 0 (tid 0-63):  16 lanes/sequence scan. xproj pre-activations are
//     staged GLOBAL->VGPR (double-buffered f2 arrays, one coalesced
//     global_load_dwordx2 per lane per t, issued a full chunk ahead) -- the
//     16-step inner loop has ZERO memory operations. h goes to a register
//     array, flushed once per chunk to bank-conflict-free padded LDS.
//   wave 1 (tid 64-127): one chunk behind; each lane owns one (seq,t) row:
//     37-logit dot + softmax + direct store to out.
// Sync: raw s_barrier + lgkmcnt(0) only (no vmcnt drain -- register staging
// is tracked by the compiler's own counted vmcnt waits).
// ---------------------------------------------------------------------------
#define TSTR 12                 // hst per-t dword stride (8 data + 4 pad)
#define SSTR (CH * TSTR + 4)    // 196: per (buffer,seq) stride

#define STEP(cur, tl) do {                                                  \
    const float pA = cur[tl].x, pB = cur[tl].y;                             \
    const float ha0 = h;                                                    \
    const float ha1 = dpp_f<0x4E>(h);                                       \
    const float ha3 = dpp_f<0x141>(h);                                      \
    const float ha2 = dpp_f<0x4E>(ha3);                                     \
    const float ha7 = dpp_f<0x140>(h);                                      \
    const float ha4 = dpp_f<0x141>(ha7);                                    \
    const float ha5 = dpp_f<0x4E>(ha4);                                     \
    const float ha6 = dpp_f<0x1B>(ha7);                                     \
    float a0 = fmaf(wA[0], ha0, pA);                                        \
    a0 = fmaf(wA[1], ha1, a0);                                              \
    a0 = fmaf(wA[2], ha2, a0);                                              \
    a0 = fmaf(wA[3], ha3, a0);                                              \
    float a1 = wA[4] * ha4;                                                 \
    a1 = fmaf(wA[5], ha5, a1);                                              \
    a1 = fmaf(wA[6], ha6, a1);                                              \
    a1 = fmaf(wA[7], ha7, a1);                                              \
    const float npA = a0 + a1;                                              \
    float b0 = fmaf(wB[0], ha0, pB);                                        \
    b0 = fmaf(wB[1], ha1, b0);                                              \
    b0 = fmaf(wB[2], ha2, b0);                                              \
    b0 = fmaf(wB[3], ha3, b0);                                              \
    float b1 = wB[4] * ha4;                                                 \
    b1 = fmaf(wB[5], ha5, b1);                                              \
    b1 = fmaf(wB[6], ha6, b1);                                              \
    b1 = fmaf(wB[7], ha7, b1);                                              \
    const float npB = b0 + b1;                                              \
    const float eA = rcp_f(1.f + exp2_f(npA));    /* r=0: i ; r=1: f */     \
    const float uB = rcp_f(1.f + exp2_f(npB));    /* r=0: raw g ; r=1: o */ \
    const float gg = fmaf(-4.f * L2E, uB, 2.f * L2E); /* -2L2E*tanh(g) */   \
    const float myU = r ? eA : eA * gg;           /* r=0: -2L2E*i*g; r=1: f */\
    const float otU = dpp_f<0xB1>(myU);                                     \
    const float fg  = r ? myU : otU;                                        \
    const float igg = r ? otU : myU;                                        \
    const float ogx = dpp_f<0xB1>(uB);                                      \
    const float og  = r ? uB : ogx;                                         \
    c = fmaf(fg, c, igg);                         /* c holds -2L2E*c_true */\
    const float rv = rcp_f(1.f + exp2_f(c));                                \
    const float og2 = og + og;                                              \
    h = fmaf(og2, rv, -og);                       /* og*(2rv-1) */          \
    hsv[tl] = h;                                                            \
} while (0)

#define CHUNK(cur, nxt, it, pbuf) do {                                      \
    if ((it) + 1 < NCH) {                                                   \
        const f2_t* src = (const f2_t*)(xp + ((it) + 1) * CHW + roff2);     \
        _Pragma("unroll")                                                   \
        for (int tl = 0; tl < CH; ++tl) nxt[tl] = src[tl * 64];             \
        __builtin_amdgcn_sched_barrier(0);                                  \
    }                                                                       \
    _Pragma("unroll")                                                       \
    for (int tl = 0; tl < CH; ++tl) STEP(cur, tl);                          \
    if (r == 0) {                                                           \
        float* hb = &hst[((pbuf) * 4 + s4) * SSTR + j];                     \
        _Pragma("unroll")                                                   \
        for (int i = 0; i < CH; ++i) hb[i * TSTR] = hsv[i];                 \
    }                                                                       \
} while (0)

#define EMIT(pk) do {                                                       \
    const int os = lane >> 4, otl = lane & 15;                              \
    const float* hp = &hst[(((pk) & 1) * 4 + os) * SSTR + otl * TSTR];      \
    const f4_t h0 = *(const f4_t*)hp;                                       \
    const f4_t h1 = *(const f4_t*)(hp + 4);                                 \
    const f4_t* W4 = (const f4_t*)Wo;                                       \
    float z[VV];                                                            \
    float m = -1e30f;                                                       \
    _Pragma("unroll")                                                       \
    for (int v = 0; v < VV; ++v) {                                          \
        const f4_t w0 = W4[v * 2], w1 = W4[v * 2 + 1];                      \
        float sv = bo[v];                                                   \
        sv = fmaf(h0.x, w0.x, sv); sv = fmaf(h0.y, w0.y, sv);               \
        sv = fmaf(h0.z, w0.z, sv); sv = fmaf(h0.w, w0.w, sv);               \
        sv = fmaf(h1.x, w1.x, sv); sv = fmaf(h1.y, w1.y, sv);               \
        sv = fmaf(h1.z, w1.z, sv); sv = fmaf(h1.w, w1.w, sv);               \
        z[v] = sv;                                                          \
        m = fmaxf(m, sv);                                                   \
    }                                                                       \
    float sum = 0.f;                                                        \
    _Pragma("unroll")                                                       \
    for (int v = 0; v < VV; ++v) {                                          \
        z[v] = exp2_f((z[v] - m) * L2E);                                    \
        sum += z[v];                                                        \
    }                                                                       \
    const float rs = rcp_f(sum);                                            \
    const int ob = bg * 4 + os;                                             \
    const int ot = (pk) * CH + otl;                                         \
    float* op = out + ((size_t)ob * TT + ot) * VV;                          \
    _Pragma("unroll")                                                       \
    for (int v = 0; v < VV; ++v) op[v] = z[v] * rs;                         \
} while (0)

__global__ __launch_bounds__(128) void k_lstm(const float* __restrict__ W_hh,
                                              const float* __restrict__ xproj,
                                              const float* __restrict__ W_out,
                                              const float* __restrict__ b_out,
                                              float* __restrict__ out) {
    __shared__ __align__(16) float hst[2 * 4 * SSTR];   // 6272 B
    __shared__ __align__(16) float Wo[VV * HH];
    __shared__ float bo[VV];

    const int tid  = threadIdx.x;
    const int wv   = tid >> 6;        // 0: scan; 1: output
    const int lane = tid & 63;
    const int bg   = blockIdx.x;      // 0..127
    const float* xp = xproj + (size_t)bg * (TT * 128);

    // scan-wave lane decode
    const int s4 = lane >> 4;
    const int q  = lane & 15;
    const int j  = q >> 1;
    const int r  = q & 1;
    const int rowA  = r * 8 + j;                 // i or f row
    const int roff2 = (rowA * 4 + s4) * 2;       // word offset of (A,B) pair

    f2_t cA[CH], cB[CH];
    float hsv[CH];
    float wA[HH], wB[HH];

    if (wv == 0) {
        const int rowB = 16 + rowA;              // g or o row
        const float scA = -L2E;
        const float scB = r ? -L2E : (-2.f * L2E);
        #pragma unroll
        for (int m = 0; m < HH; ++m) {
            wA[m] = scA * W_hh[rowA * HH + (j ^ m)];
            wB[m] = scB * W_hh[rowB * HH + (j ^ m)];
        }
        // prefetch chunk 0 into cA
        const f2_t* src = (const f2_t*)(xp + roff2);
        #pragma unroll
        for (int tl = 0; tl < CH; ++tl) cA[tl] = src[tl * 64];
    } else {
        for (int i = lane; i < VV * HH; i += 64) Wo[i] = W_out[i];
        if (lane < VV) bo[lane] = b_out[lane];
    }

    float h = 0.f, c = 0.f;

    // 18 slots (9 outer x 2), slots 0..16 active: wave0 computes chunk `it`
    // (it<16), wave1 emits chunk `it-1` (1<=it<=16). 17 barriers, uniform.
    for (int ou = 0; ou < 9; ++ou) {
        {
            const int it = ou * 2;
            if (wv == 0) {
                if (it < NCH) CHUNK(cA, cB, it, 0);
            } else if (it >= 1 && it <= NCH) {
                EMIT(it - 1);
            }
            asm volatile("s_waitcnt lgkmcnt(0)" ::: "memory");
            __builtin_amdgcn_s_barrier();
            __builtin_amdgcn_sched_barrier(0);
        }
        {
            const int it = ou * 2 + 1;
            if (it <= NCH) {
                if (wv == 0) {
                    if (it < NCH) CHUNK(cB, cA, it, 1);
                } else {
                    EMIT(it - 1);
                }
                asm volatile("s_waitcnt lgkmcnt(0)" ::: "memory");
                __builtin_amdgcn_s_barrier();
                __builtin_amdgcn_sched_barrier(0);
            }
        }
    }
}

// ---------------------------------------------------------------------------
// Workspace (floats): featp@0 (4*512*37=75,776) | xproj@81920 (4,194,304)
// ---------------------------------------------------------------------------
extern "C" void kernel_launch(void* const* d_in, const int* in_sizes, int n_in,
                              void* d_out, int out_size, void* d_ws, size_t ws_size,
                              hipStream_t stream) {
    const float* features = (const float*)d_in[0];
    const float* captions = (const float*)d_in[1];
    const float* W_in     = (const float*)d_in[2];
    const float* b_in     = (const float*)d_in[3];
    const float* W_ih     = (const float*)d_in[4];
    const float* W_hh     = (const float*)d_in[5];
    const float* b_ih     = (const float*)d_in[6];
    const float* b_hh     = (const float*)d_in[7];
    const float* W_out    = (const float*)d_in[8];
    const float* b_out    = (const float*)d_in[9];
    float* out = (float*)d_out;

    float* ws    = (float*)d_ws;
    float* featp = ws;
    float* xproj = ws + 81920;

    k_feat <<<dim3(BB, 4),  256, 0, stream>>>(features, W_in, b_in, featp);
    k_xproj<<<dim3(128, 8), 256, 0, stream>>>(captions, W_ih, b_ih, b_hh, featp, xproj);
    k_lstm <<<128,          128, 0, stream>>>(W_hh, xproj, W_out, b_out, out);
}